// Round 10
// baseline (143.773 us; speedup 1.0000x reference)
//
#include <hip/hip_runtime.h>
#include <hip/hip_fp16.h>
#include <math.h>

#define NQ   100000
#define CCH  128
#define HDIM 256
#define WDIM 256
#define HW   (HDIM * WDIM)
#define KPTS 4
#define PDIM 36
#define NBIN 4096   // 16x16x16 Morton bins
#define RECW 76     // u32/record: qidx + 12*(4 byte-addr + w01 + w23) + pad

#define WBLK ((NQ + 255) / 256)          // 391 scatter+weights blocks
#define TBLK ((HW / 64) * (CCH / 64) * 3) // 6144 transpose blocks

typedef float floatx4 __attribute__((ext_vector_type(4)));

__device__ inline int axis_bin(float x) {
  int b = (int)((x + 1.0f) * 8.0f);
  return min(15, max(0, b));
}
__device__ inline unsigned int spread4(unsigned int x) {
  return (x & 1u) | ((x & 2u) << 2) | ((x & 4u) << 4) | ((x & 8u) << 6);
}
__device__ inline unsigned int bin_of(float x, float y, float z) {
  return spread4((unsigned int)axis_bin(x)) |
         (spread4((unsigned int)axis_bin(y)) << 1) |
         (spread4((unsigned int)axis_bin(z)) << 2);
}

// ---------------- sort pipeline ----------------
__global__ void hist_kernel(const float* __restrict__ query,
                            unsigned int* __restrict__ counts) {
  const int q = blockIdx.x * 256 + threadIdx.x;
  if (q >= NQ) return;
  const unsigned int b = bin_of(query[q * 3 + 0], query[q * 3 + 1], query[q * 3 + 2]);
  atomicAdd(&counts[b], 1u);
}

// 4096-bin exclusive scan: 1024 threads x 4 bins each
__global__ void scan_kernel(const unsigned int* __restrict__ counts,
                            unsigned int* __restrict__ offs) {
  __shared__ unsigned int s[1024];
  const int t = threadIdx.x;
  const unsigned int c0 = counts[4 * t + 0];
  const unsigned int c1 = counts[4 * t + 1];
  const unsigned int c2 = counts[4 * t + 2];
  const unsigned int c3 = counts[4 * t + 3];
  const unsigned int sum = c0 + c1 + c2 + c3;
  s[t] = sum;
  __syncthreads();
  for (int d = 1; d < 1024; d <<= 1) {
    const unsigned int v = (t >= d) ? s[t - d] : 0u;
    __syncthreads();
    s[t] += v;
    __syncthreads();
  }
  const unsigned int base = s[t] - sum;  // exclusive prefix
  offs[4 * t + 0] = base;
  offs[4 * t + 1] = base + c0;
  offs[4 * t + 2] = base + c0 + c1;
  offs[4 * t + 3] = base + c0 + c1 + c2;
}

// ==== fused: blocks [0,WBLK) scatter+weights ; blocks [WBLK,WBLK+TBLK) transpose ====
__global__ void fused_prep_kernel(const float* __restrict__ f0,
                                  const float* __restrict__ f1,
                                  const float* __restrict__ f2,
                                  __half2* __restrict__ featT,
                                  const float* __restrict__ query,
                                  const float* __restrict__ pe,
                                  unsigned int* __restrict__ offs,
                                  const float* __restrict__ Wa0, const float* __restrict__ ba0,
                                  const float* __restrict__ Wo0, const float* __restrict__ bo0,
                                  const float* __restrict__ Wa1, const float* __restrict__ ba1,
                                  const float* __restrict__ Wo1, const float* __restrict__ bo1,
                                  const float* __restrict__ Wa2, const float* __restrict__ ba2,
                                  const float* __restrict__ Wo2, const float* __restrict__ bo2,
                                  unsigned int* __restrict__ rec) {
  __shared__ float smem[64 * 65];  // transpose tile / weights W-cache (aliased)
  const int bx = blockIdx.x;
  const int t = threadIdx.x;

  if (bx >= WBLK) {
    // ---------------- transpose + f16 downconvert ----------------
    float (*tile)[65] = (float (*)[65])smem;
    const int tb = bx - WBLK;
    const int plane = tb >> 11;            // 2048 blocks per plane
    const int c64 = (tb >> 10) & 1;        // 2 channel-blocks
    const int hw64 = tb & 1023;            // 1024 hw-blocks
    const float* __restrict__ f = (plane == 0) ? f0 : ((plane == 1) ? f1 : f2);
    __half2* __restrict__ o = featT + (size_t)plane * (size_t)HW * (CCH / 2);
    const int hw0 = hw64 * 64;
    const int c0 = c64 * 64;
    const int c_l = t >> 6;     // 0..3
    const int hw_l = t & 63;    // 0..63
#pragma unroll
    for (int i = 0; i < 16; ++i) {
      tile[c_l + 4 * i][hw_l] = f[(size_t)(c0 + c_l + 4 * i) * HW + (hw0 + hw_l)];
    }
    __syncthreads();
#pragma unroll
    for (int i = 0; i < 8; ++i) {
      const int idx = t + 256 * i;
      const int j = idx & 31;   // channel-pair within tile
      const int r = idx >> 5;   // hw row within tile (0..63)
      o[(size_t)(hw0 + r) * (CCH / 2) + (c0 / 2 + j)] =
          __floats2half2_rn(tile[2 * j][r], tile[2 * j + 1][r]);
    }
    return;
  }

  // ---------------- scatter + weights -> sorted compact record ----------------
  float* sWa = smem;           // [3][36][4] = 432
  float* sWo = smem + 432;     // [3][36][8] = 864
  float* sba = smem + 1296;    // [3][4]
  float* sbo = smem + 1308;    // [3][8]
  {
    for (int i = t; i < 144; i += 256) { sWa[i] = Wa0[i]; sWa[144 + i] = Wa1[i]; sWa[288 + i] = Wa2[i]; }
    for (int i = t; i < 288; i += 256) { sWo[i] = Wo0[i]; sWo[288 + i] = Wo1[i]; sWo[576 + i] = Wo2[i]; }
    if (t < 4) { sba[0 + t] = ba0[t]; sba[4 + t] = ba1[t]; sba[8 + t] = ba2[t]; }
    if (t < 8) { sbo[0 + t] = bo0[t]; sbo[8 + t] = bo1[t]; sbo[16 + t] = bo2[t]; }
  }
  __syncthreads();

  const int q = bx * 256 + t;
  if (q >= NQ) return;

  float p[PDIM];
  const float4* pe4 = (const float4*)(pe + (size_t)q * PDIM);
#pragma unroll
  for (int i = 0; i < 9; ++i) {
    float4 v = pe4[i];
    p[4 * i + 0] = v.x; p[4 * i + 1] = v.y; p[4 * i + 2] = v.z; p[4 * i + 3] = v.w;
  }

  float la[3][4], of[3][8];
#pragma unroll
  for (int pl = 0; pl < 3; ++pl) {
#pragma unroll
    for (int k = 0; k < 4; ++k) la[pl][k] = sba[pl * 4 + k];
#pragma unroll
    for (int d = 0; d < 8; ++d) of[pl][d] = sbo[pl * 8 + d];
  }
#pragma unroll 4
  for (int j = 0; j < PDIM; ++j) {
    const float pj = p[j];
#pragma unroll
    for (int pl = 0; pl < 3; ++pl) {
#pragma unroll
      for (int k = 0; k < 4; ++k) la[pl][k] = fmaf(pj, sWa[(pl * PDIM + j) * 4 + k], la[pl][k]);
#pragma unroll
      for (int d = 0; d < 8; ++d) of[pl][d] = fmaf(pj, sWo[(pl * PDIM + j) * 8 + d], of[pl][d]);
    }
  }

  const float qx = query[q * 3 + 0];
  const float qy = query[q * 3 + 1];
  const float qz = query[q * 3 + 2];

  const unsigned int bin = bin_of(qx, qy, qz);
  const unsigned int pos = atomicAdd(&offs[bin], 1u);
  unsigned int* r = rec + (size_t)pos * RECW;
  r[0] = (unsigned int)q;

#pragma unroll
  for (int pl = 0; pl < 3; ++pl) {
    const float m = fmaxf(fmaxf(la[pl][0], la[pl][1]), fmaxf(la[pl][2], la[pl][3]));
    const float e0 = expf(la[pl][0] - m);
    const float e1 = expf(la[pl][1] - m);
    const float e2 = expf(la[pl][2] - m);
    const float e3 = expf(la[pl][3] - m);
    const float inv = 1.0f / (e0 + e1 + e2 + e3);
    float at[4] = {e0 * inv, e1 * inv, e2 * inv, e3 * inv};

    // coords pair per plane: xy:(q0,q1) xz:(q0,q2) yz:(q1,q2)
    const float ca = (pl == 2) ? qy : qx;   // coords[...,0] -> gy
    const float cb = (pl == 0) ? qy : qz;   // coords[...,1] -> gx
    const unsigned int pbase = (unsigned int)pl * (unsigned int)HW * (CCH / 2);
#pragma unroll
    for (int k = 0; k < KPTS; ++k) {
      const float gy = ca + of[pl][k * 2 + 0];
      const float gx = cb + of[pl][k * 2 + 1];
      float x = ((gx + 1.0f) * (float)WDIM - 1.0f) * 0.5f;
      float y = ((gy + 1.0f) * (float)HDIM - 1.0f) * 0.5f;
      x = fminf(fmaxf(x, 0.0f), (float)(WDIM - 1));
      y = fminf(fmaxf(y, 0.0f), (float)(HDIM - 1));
      const float x0f = floorf(x), y0f = floorf(y);
      const float wx = x - x0f, wy = y - y0f;
      const int xi0 = (int)x0f, yi0 = (int)y0f;
      const unsigned int dx = (xi0 + 1 <= WDIM - 1) ? 64u : 0u;      // +1 px in x = 64 half2
      const unsigned int dy = (yi0 + 1 <= HDIM - 1) ? 16384u : 0u;   // +1 px in y = 256*64
      const float a = at[k];
      const float w00 = a * (1.0f - wx) * (1.0f - wy);
      const float w01 = a * wx * (1.0f - wy);
      const float w10 = a * (1.0f - wx) * wy;
      const float w11 = a * wx * wy;
      const unsigned int a00 = (pbase + (unsigned int)(yi0 * WDIM + xi0) * (CCH / 2)) * 4u; // BYTES
      const int j = pl * 4 + k;
      unsigned int* g = r + 1 + 6 * j;
      g[0] = a00;
      g[1] = a00 + dx * 4u;
      g[2] = a00 + dy * 4u;
      g[3] = a00 + (dx + dy) * 4u;
      const __half2 h01 = __floats2half2_rn(w00, w01);
      const __half2 h23 = __floats2half2_rn(w10, w11);
      g[4] = *(const unsigned int*)&h01;
      g[5] = *(const unsigned int*)&h23;
    }
  }
  r[73] = 0u; r[74] = 0u; r[75] = 0u;
}

// ---- main gather: 1 wave/query; 1 dwordx4 load covers all 4 corners of a point ----
// lane = 16*g + l : corner g, channels 8l..8l+7. Butterfly-reduce over g at the end.
__global__ void sample_kernel(const unsigned int* __restrict__ rec,
                              const __half2* __restrict__ featT,
                              float* __restrict__ out) {
  const int lane = threadIdx.x & 63;
  const int wid = threadIdx.x >> 6;
  // bijective XCD chunk swizzle: 25000 blocks, 8 XCDs, 25000 % 8 == 0
  const int b = blockIdx.x;
  const int sb = (b & 7) * 3125 + (b >> 3);
  int i = sb * 4 + wid;
  i = __builtin_amdgcn_readfirstlane(i);   // wave-uniform sorted index

  const unsigned int* __restrict__ r = rec + (size_t)i * RECW;
  const int q = (int)r[0];

  const int g = lane >> 4;                    // corner id 0..3
  const unsigned int l16 = (lane & 15) * 16;  // byte offset within corner block
  const bool gx1 = (g & 1) != 0;
  const bool gy1 = (g & 2) != 0;
  const char* __restrict__ base = (const char*)featT;

  // phase 1: per-lane corner byte-address (2 cndmask + add) + weight select
  unsigned int addr[12];
  float w[12];
#pragma unroll
  for (int j = 0; j < 12; ++j) {
    const unsigned int a00 = r[1 + 6 * j + 0];
    const unsigned int a01 = r[1 + 6 * j + 1];
    const unsigned int a10 = r[1 + 6 * j + 2];
    const unsigned int a11 = r[1 + 6 * j + 3];
    const unsigned int w01u = r[1 + 6 * j + 4];
    const unsigned int w23u = r[1 + 6 * j + 5];
    const unsigned int lo = gx1 ? a01 : a00;
    const unsigned int hi = gx1 ? a11 : a10;
    addr[j] = (gy1 ? hi : lo) + l16;
    const unsigned int hv = gy1 ? w23u : w01u;
    const unsigned int hw = gx1 ? (hv >> 16) : (hv & 0xFFFFu);
    w[j] = __low2float(__builtin_bit_cast(__half2, hw));
  }

  // phase 2: 12 dwordx4 gathers (16B/lane, 4 corners per instruction)
  uint4 v[12];
#pragma unroll
  for (int j = 0; j < 12; ++j) {
    v[j] = *(const uint4*)(base + addr[j]);
  }

  // phase 3: weighted accumulate (8 channels per lane)
  float acc[8] = {0.f, 0.f, 0.f, 0.f, 0.f, 0.f, 0.f, 0.f};
#pragma unroll
  for (int j = 0; j < 12; ++j) {
    const __half2 h0 = __builtin_bit_cast(__half2, v[j].x);
    const __half2 h1 = __builtin_bit_cast(__half2, v[j].y);
    const __half2 h2 = __builtin_bit_cast(__half2, v[j].z);
    const __half2 h3 = __builtin_bit_cast(__half2, v[j].w);
    const float wj = w[j];
    acc[0] = fmaf(wj, __low2float(h0), acc[0]);
    acc[1] = fmaf(wj, __high2float(h0), acc[1]);
    acc[2] = fmaf(wj, __low2float(h1), acc[2]);
    acc[3] = fmaf(wj, __high2float(h1), acc[3]);
    acc[4] = fmaf(wj, __low2float(h2), acc[4]);
    acc[5] = fmaf(wj, __high2float(h2), acc[5]);
    acc[6] = fmaf(wj, __low2float(h3), acc[6]);
    acc[7] = fmaf(wj, __high2float(h3), acc[7]);
  }

  // phase 4: butterfly-reduce the 4 corner groups (lanes l, l+16, l+32, l+48)
#pragma unroll
  for (int c = 0; c < 8; ++c) acc[c] += __shfl_xor(acc[c], 32, 64);
#pragma unroll
  for (int c = 0; c < 8; ++c) acc[c] += __shfl_xor(acc[c], 16, 64);

  if (lane < 16) {
    float* op = out + (size_t)q * CCH + lane * 8;
    floatx4 lo4 = {acc[0], acc[1], acc[2], acc[3]};
    floatx4 hi4 = {acc[4], acc[5], acc[6], acc[7]};
    __builtin_nontemporal_store(lo4, (floatx4*)op);
    __builtin_nontemporal_store(hi4, (floatx4*)(op + 4));
  }
}

// -------- fallback: fused, direct (C,H,W) gather (used only if ws too small) --------
__global__ void fused_fallback(const float* __restrict__ query,
                               const float* __restrict__ pe,
                               const float* __restrict__ f0,
                               const float* __restrict__ f1,
                               const float* __restrict__ f2,
                               const float* __restrict__ Wa0, const float* __restrict__ ba0,
                               const float* __restrict__ Wo0, const float* __restrict__ bo0,
                               const float* __restrict__ Wa1, const float* __restrict__ ba1,
                               const float* __restrict__ Wo1, const float* __restrict__ bo1,
                               const float* __restrict__ Wa2, const float* __restrict__ ba2,
                               const float* __restrict__ Wo2, const float* __restrict__ bo2,
                               float* __restrict__ out) {
  const int lane = threadIdx.x & 63;
  const int wid = threadIdx.x >> 6;
  int q = blockIdx.x * 4 + wid;
  q = __builtin_amdgcn_readfirstlane(q);
  if (q >= NQ) return;
  const float qx = query[q * 3 + 0];
  const float qy = query[q * 3 + 1];
  const float qz = query[q * 3 + 2];
  const float* pep = pe + (size_t)q * PDIM;
  const int c0i = lane * 2, c1i = lane * 2 + 1;
  float accx = 0.0f, accy = 0.0f;
#pragma unroll
  for (int pl = 0; pl < 3; ++pl) {
    const float* Wa = (pl == 0) ? Wa0 : ((pl == 1) ? Wa1 : Wa2);
    const float* ba = (pl == 0) ? ba0 : ((pl == 1) ? ba1 : ba2);
    const float* Wo = (pl == 0) ? Wo0 : ((pl == 1) ? Wo1 : Wo2);
    const float* bo = (pl == 0) ? bo0 : ((pl == 1) ? bo1 : bo2);
    const float* f = (pl == 0) ? f0 : ((pl == 1) ? f1 : f2);
    float la[4] = {ba[0], ba[1], ba[2], ba[3]};
    float of[8];
    for (int d = 0; d < 8; ++d) of[d] = bo[d];
    for (int j = 0; j < PDIM; ++j) {
      const float pj = pep[j];
      for (int k = 0; k < 4; ++k) la[k] = fmaf(pj, Wa[j * 4 + k], la[k]);
      for (int d = 0; d < 8; ++d) of[d] = fmaf(pj, Wo[j * 8 + d], of[d]);
    }
    const float m = fmaxf(fmaxf(la[0], la[1]), fmaxf(la[2], la[3]));
    float e[4], s = 0.0f;
    for (int k = 0; k < 4; ++k) { e[k] = expf(la[k] - m); s += e[k]; }
    const float inv = 1.0f / s;
    const float ca = (pl == 2) ? qy : qx;
    const float cb = (pl == 0) ? qy : qz;
    for (int k = 0; k < 4; ++k) {
      const float gy = ca + of[k * 2 + 0];
      const float gx = cb + of[k * 2 + 1];
      float x = ((gx + 1.0f) * (float)WDIM - 1.0f) * 0.5f;
      float y = ((gy + 1.0f) * (float)HDIM - 1.0f) * 0.5f;
      x = fminf(fmaxf(x, 0.0f), (float)(WDIM - 1));
      y = fminf(fmaxf(y, 0.0f), (float)(HDIM - 1));
      const float x0f = floorf(x), y0f = floorf(y);
      const float wx = x - x0f, wy = y - y0f;
      const int xi0 = (int)x0f, yi0 = (int)y0f;
      const int xi1 = min(xi0 + 1, WDIM - 1);
      const int yi1 = min(yi0 + 1, HDIM - 1);
      const float a = e[k] * inv;
      const float w00 = a * (1.0f - wx) * (1.0f - wy);
      const float w01 = a * wx * (1.0f - wy);
      const float w10 = a * (1.0f - wx) * wy;
      const float w11 = a * wx * wy;
      const size_t p00 = (size_t)(yi0 * WDIM + xi0);
      const size_t p01 = (size_t)(yi0 * WDIM + xi1);
      const size_t p10 = (size_t)(yi1 * WDIM + xi0);
      const size_t p11 = (size_t)(yi1 * WDIM + xi1);
      const float* fa = f + (size_t)c0i * HW;
      const float* fb = f + (size_t)c1i * HW;
      accx += w00 * fa[p00] + w01 * fa[p01] + w10 * fa[p10] + w11 * fa[p11];
      accy += w00 * fb[p00] + w01 * fb[p01] + w10 * fb[p10] + w11 * fb[p11];
    }
  }
  *(float2*)(out + (size_t)q * CCH + lane * 2) = make_float2(accx, accy);
}

extern "C" void kernel_launch(void* const* d_in, const int* in_sizes, int n_in,
                              void* d_out, int out_size, void* d_ws, size_t ws_size,
                              hipStream_t stream) {
  const float* query = (const float*)d_in[0];
  const float* pe    = (const float*)d_in[1];
  const float* feat0 = (const float*)d_in[2];
  const float* Wa0   = (const float*)d_in[3];
  const float* ba0   = (const float*)d_in[4];
  const float* Wo0   = (const float*)d_in[5];
  const float* bo0   = (const float*)d_in[6];
  const float* feat1 = (const float*)d_in[7];
  const float* Wa1   = (const float*)d_in[8];
  const float* ba1   = (const float*)d_in[9];
  const float* Wo1   = (const float*)d_in[10];
  const float* bo1   = (const float*)d_in[11];
  const float* feat2 = (const float*)d_in[12];
  const float* Wa2   = (const float*)d_in[13];
  const float* ba2   = (const float*)d_in[14];
  const float* Wo2   = (const float*)d_in[15];
  const float* bo2   = (const float*)d_in[16];
  float* out = (float*)d_out;

  const size_t featT_elems = 3ull * HW * (CCH / 2);  // __half2 count
  // layout: featT (half2) | rec (NQ*RECW u32) | counts | offs
  const size_t need = featT_elems * 4 + (size_t)NQ * RECW * 4 + (size_t)NBIN * 8;

  if (ws_size >= need) {
    __half2* featT = (__half2*)d_ws;
    unsigned int* rec = (unsigned int*)(d_ws) + featT_elems;  // featT is 4B elems
    unsigned int* counts = rec + (size_t)NQ * RECW;
    unsigned int* offs = counts + NBIN;

    (void)hipMemsetAsync(counts, 0, NBIN * sizeof(unsigned int), stream);
    hist_kernel<<<dim3(WBLK), dim3(256), 0, stream>>>(query, counts);
    scan_kernel<<<dim3(1), dim3(1024), 0, stream>>>(counts, offs);
    fused_prep_kernel<<<dim3(WBLK + TBLK), dim3(256), 0, stream>>>(
        feat0, feat1, feat2, featT, query, pe, offs,
        Wa0, ba0, Wo0, bo0, Wa1, ba1, Wo1, bo1, Wa2, ba2, Wo2, bo2, rec);
    sample_kernel<<<dim3(NQ / 4), dim3(256), 0, stream>>>(rec, featT, out);
  } else {
    fused_fallback<<<dim3((NQ + 3) / 4), dim3(256), 0, stream>>>(
        query, pe, feat0, feat1, feat2,
        Wa0, ba0, Wo0, bo0, Wa1, ba1, Wo1, bo1, Wa2, ba2, Wo2, bo2, out);
  }
}

// Round 11
// 126.906 us; speedup vs baseline: 1.1329x; 1.1329x over previous
//
#include <hip/hip_runtime.h>
#include <hip/hip_fp16.h>
#include <math.h>

#define NQ   100000
#define CCH  128
#define HDIM 256
#define WDIM 256
#define HW   (HDIM * WDIM)
#define KPTS 4
#define PDIM 36
#define NBIN 4096   // 16x16x16 Morton bins
#define RECW 40     // u32 per sorted-query record: qidx + 12*(addr,w01,w23) + pad

#define WBLK ((NQ + 255) / 256)          // 391 scatter+weights blocks
#define TBLK ((HW / 64) * (CCH / 64) * 3) // 6144 transpose blocks

typedef float floatx4 __attribute__((ext_vector_type(4)));

__device__ inline int axis_bin(float x) {
  int b = (int)((x + 1.0f) * 8.0f);
  return min(15, max(0, b));
}
__device__ inline unsigned int spread4(unsigned int x) {
  return (x & 1u) | ((x & 2u) << 2) | ((x & 4u) << 4) | ((x & 8u) << 6);
}
__device__ inline unsigned int bin_of(float x, float y, float z) {
  return spread4((unsigned int)axis_bin(x)) |
         (spread4((unsigned int)axis_bin(y)) << 1) |
         (spread4((unsigned int)axis_bin(z)) << 2);
}

// ---------------- sort pipeline ----------------
__global__ void hist_kernel(const float* __restrict__ query,
                            unsigned int* __restrict__ counts) {
  const int q = blockIdx.x * 256 + threadIdx.x;
  if (q >= NQ) return;
  const unsigned int b = bin_of(query[q * 3 + 0], query[q * 3 + 1], query[q * 3 + 2]);
  atomicAdd(&counts[b], 1u);
}

// 4096-bin exclusive scan: 1024 threads x 4 bins each
__global__ void scan_kernel(const unsigned int* __restrict__ counts,
                            unsigned int* __restrict__ offs) {
  __shared__ unsigned int s[1024];
  const int t = threadIdx.x;
  const unsigned int c0 = counts[4 * t + 0];
  const unsigned int c1 = counts[4 * t + 1];
  const unsigned int c2 = counts[4 * t + 2];
  const unsigned int c3 = counts[4 * t + 3];
  const unsigned int sum = c0 + c1 + c2 + c3;
  s[t] = sum;
  __syncthreads();
  for (int d = 1; d < 1024; d <<= 1) {
    const unsigned int v = (t >= d) ? s[t - d] : 0u;
    __syncthreads();
    s[t] += v;
    __syncthreads();
  }
  const unsigned int base = s[t] - sum;  // exclusive prefix
  offs[4 * t + 0] = base;
  offs[4 * t + 1] = base + c0;
  offs[4 * t + 2] = base + c0 + c1;
  offs[4 * t + 3] = base + c0 + c1 + c2;
}

// ==== fused: blocks [0,WBLK) scatter+weights ; blocks [WBLK,WBLK+TBLK) transpose ====
__global__ void fused_prep_kernel(const float* __restrict__ f0,
                                  const float* __restrict__ f1,
                                  const float* __restrict__ f2,
                                  __half2* __restrict__ featT,
                                  const float* __restrict__ query,
                                  const float* __restrict__ pe,
                                  unsigned int* __restrict__ offs,
                                  const float* __restrict__ Wa0, const float* __restrict__ ba0,
                                  const float* __restrict__ Wo0, const float* __restrict__ bo0,
                                  const float* __restrict__ Wa1, const float* __restrict__ ba1,
                                  const float* __restrict__ Wo1, const float* __restrict__ bo1,
                                  const float* __restrict__ Wa2, const float* __restrict__ ba2,
                                  const float* __restrict__ Wo2, const float* __restrict__ bo2,
                                  unsigned int* __restrict__ rec) {
  __shared__ float smem[64 * 65];  // transpose tile / weights W-cache (aliased)
  const int bx = blockIdx.x;
  const int t = threadIdx.x;

  if (bx >= WBLK) {
    // ---------------- transpose + f16 downconvert ----------------
    float (*tile)[65] = (float (*)[65])smem;
    const int tb = bx - WBLK;
    const int plane = tb >> 11;            // 2048 blocks per plane
    const int c64 = (tb >> 10) & 1;        // 2 channel-blocks
    const int hw64 = tb & 1023;            // 1024 hw-blocks
    const float* __restrict__ f = (plane == 0) ? f0 : ((plane == 1) ? f1 : f2);
    __half2* __restrict__ o = featT + (size_t)plane * (size_t)HW * (CCH / 2);
    const int hw0 = hw64 * 64;
    const int c0 = c64 * 64;
    const int c_l = t >> 6;     // 0..3
    const int hw_l = t & 63;    // 0..63
#pragma unroll
    for (int i = 0; i < 16; ++i) {
      tile[c_l + 4 * i][hw_l] = f[(size_t)(c0 + c_l + 4 * i) * HW + (hw0 + hw_l)];
    }
    __syncthreads();
#pragma unroll
    for (int i = 0; i < 8; ++i) {
      const int idx = t + 256 * i;
      const int j = idx & 31;   // channel-pair within tile
      const int r = idx >> 5;   // hw row within tile (0..63)
      o[(size_t)(hw0 + r) * (CCH / 2) + (c0 / 2 + j)] =
          __floats2half2_rn(tile[2 * j][r], tile[2 * j + 1][r]);
    }
    return;
  }

  // ---------------- scatter + weights -> sorted compact record ----------------
  float* sWa = smem;           // [3][36][4] = 432
  float* sWo = smem + 432;     // [3][36][8] = 864
  float* sba = smem + 1296;    // [3][4]
  float* sbo = smem + 1308;    // [3][8]
  {
    for (int i = t; i < 144; i += 256) { sWa[i] = Wa0[i]; sWa[144 + i] = Wa1[i]; sWa[288 + i] = Wa2[i]; }
    for (int i = t; i < 288; i += 256) { sWo[i] = Wo0[i]; sWo[288 + i] = Wo1[i]; sWo[576 + i] = Wo2[i]; }
    if (t < 4) { sba[0 + t] = ba0[t]; sba[4 + t] = ba1[t]; sba[8 + t] = ba2[t]; }
    if (t < 8) { sbo[0 + t] = bo0[t]; sbo[8 + t] = bo1[t]; sbo[16 + t] = bo2[t]; }
  }
  __syncthreads();

  const int q = bx * 256 + t;
  if (q >= NQ) return;

  float p[PDIM];
  const float4* pe4 = (const float4*)(pe + (size_t)q * PDIM);
#pragma unroll
  for (int i = 0; i < 9; ++i) {
    float4 v = pe4[i];
    p[4 * i + 0] = v.x; p[4 * i + 1] = v.y; p[4 * i + 2] = v.z; p[4 * i + 3] = v.w;
  }

  float la[3][4], of[3][8];
#pragma unroll
  for (int pl = 0; pl < 3; ++pl) {
#pragma unroll
    for (int k = 0; k < 4; ++k) la[pl][k] = sba[pl * 4 + k];
#pragma unroll
    for (int d = 0; d < 8; ++d) of[pl][d] = sbo[pl * 8 + d];
  }
#pragma unroll 4
  for (int j = 0; j < PDIM; ++j) {
    const float pj = p[j];
#pragma unroll
    for (int pl = 0; pl < 3; ++pl) {
#pragma unroll
      for (int k = 0; k < 4; ++k) la[pl][k] = fmaf(pj, sWa[(pl * PDIM + j) * 4 + k], la[pl][k]);
#pragma unroll
      for (int d = 0; d < 8; ++d) of[pl][d] = fmaf(pj, sWo[(pl * PDIM + j) * 8 + d], of[pl][d]);
    }
  }

  const float qx = query[q * 3 + 0];
  const float qy = query[q * 3 + 1];
  const float qz = query[q * 3 + 2];

  const unsigned int bin = bin_of(qx, qy, qz);
  const unsigned int pos = atomicAdd(&offs[bin], 1u);
  unsigned int* r = rec + (size_t)pos * RECW;
  r[0] = (unsigned int)q;

#pragma unroll
  for (int pl = 0; pl < 3; ++pl) {
    const float m = fmaxf(fmaxf(la[pl][0], la[pl][1]), fmaxf(la[pl][2], la[pl][3]));
    const float e0 = expf(la[pl][0] - m);
    const float e1 = expf(la[pl][1] - m);
    const float e2 = expf(la[pl][2] - m);
    const float e3 = expf(la[pl][3] - m);
    const float inv = 1.0f / (e0 + e1 + e2 + e3);
    float at[4] = {e0 * inv, e1 * inv, e2 * inv, e3 * inv};

    // coords pair per plane: xy:(q0,q1) xz:(q0,q2) yz:(q1,q2)
    const float ca = (pl == 2) ? qy : qx;   // coords[...,0] -> gy
    const float cb = (pl == 0) ? qy : qz;   // coords[...,1] -> gx
    const unsigned int pbase = (unsigned int)pl * (unsigned int)HW * (CCH / 2);
#pragma unroll
    for (int k = 0; k < KPTS; ++k) {
      const float gy = ca + of[pl][k * 2 + 0];
      const float gx = cb + of[pl][k * 2 + 1];
      float x = ((gx + 1.0f) * (float)WDIM - 1.0f) * 0.5f;
      float y = ((gy + 1.0f) * (float)HDIM - 1.0f) * 0.5f;
      x = fminf(fmaxf(x, 0.0f), (float)(WDIM - 1));
      y = fminf(fmaxf(y, 0.0f), (float)(HDIM - 1));
      const float x0f = floorf(x), y0f = floorf(y);
      const float wx = x - x0f, wy = y - y0f;
      const int xi0 = (int)x0f, yi0 = (int)y0f;
      const unsigned int dx = (xi0 + 1 <= WDIM - 1) ? 1u : 0u;
      const unsigned int dy = (yi0 + 1 <= HDIM - 1) ? 1u : 0u;
      const float a = at[k];
      const float w00 = a * (1.0f - wx) * (1.0f - wy);
      const float w01 = a * wx * (1.0f - wy);
      const float w10 = a * (1.0f - wx) * wy;
      const float w11 = a * wx * wy;
      const unsigned int a00 = pbase + (unsigned int)(yi0 * WDIM + xi0) * (CCH / 2);
      const int j = pl * 4 + k;
      r[1 + 3 * j] = a00 | (dx << 24) | (dy << 25);
      const __half2 h01 = __floats2half2_rn(w00, w01);
      const __half2 h23 = __floats2half2_rn(w10, w11);
      r[2 + 3 * j] = *(const unsigned int*)&h01;
      r[3 + 3 * j] = *(const unsigned int*)&h23;
    }
  }
  r[37] = 0u; r[38] = 0u; r[39] = 0u;
}

// ---- main gather: 1 wave/query; 1 dwordx4 load covers all 4 corners of a point ----
// lane = 16*g + l : corner g, channels 8l..8l+7. Butterfly-reduce over g at the end.
__global__ void sample_kernel(const unsigned int* __restrict__ rec,
                              const __half2* __restrict__ featT,
                              float* __restrict__ out) {
  const int lane = threadIdx.x & 63;
  const int wid = threadIdx.x >> 6;
  // bijective XCD chunk swizzle: 25000 blocks, 8 XCDs, 25000 % 8 == 0
  const int b = blockIdx.x;
  const int sb = (b & 7) * 3125 + (b >> 3);
  int i = sb * 4 + wid;
  i = __builtin_amdgcn_readfirstlane(i);   // wave-uniform sorted index

  const unsigned int* __restrict__ r = rec + (size_t)i * RECW;
  const int q = (int)r[0];

  const int g = lane >> 4;                  // corner id 0..3
  const unsigned int l4 = (lane & 15) * 4;  // half2 offset within corner block
  const unsigned int m1 = (g & 1) ? 0xFFFFFFFFu : 0u;
  const unsigned int m2 = (g & 2) ? 0xFFFFFFFFu : 0u;

  // phase 1: decode descriptors -> per-lane corner address + per-lane weight (f16 bits)
  unsigned int addr[12];
  float w[12];
#pragma unroll
  for (int j = 0; j < 12; ++j) {
    const unsigned int pk = __builtin_amdgcn_readfirstlane(r[1 + 3 * j]);
    const unsigned int w01u = __builtin_amdgcn_readfirstlane(r[2 + 3 * j]);
    const unsigned int w23u = __builtin_amdgcn_readfirstlane(r[3 + 3 * j]);
    const unsigned int a00 = pk & 0xFFFFFFu;
    const unsigned int xo = (pk >> 18) & 64u;      // dx<<6
    const unsigned int yo = (pk >> 11) & 16384u;   // dy<<14 (=256*64)
    addr[j] = a00 + (xo & m1) + (yo & m2) + l4;
    const unsigned int hv = m2 ? w23u : w01u;                       // g<2 -> (w00,w01)
    const unsigned int hw = m1 ? (hv >> 16) : (hv & 0xFFFFu);       // odd g -> high half
    w[j] = __low2float(__builtin_bit_cast(__half2, hw));
  }

  // phase 2: 12 dwordx4 gathers (16B/lane, 4 corners per instruction)
  uint4 v[12];
#pragma unroll
  for (int j = 0; j < 12; ++j) {
    v[j] = *(const uint4*)(featT + addr[j]);
  }

  // phase 3: weighted accumulate (8 channels per lane)
  float acc[8] = {0.f, 0.f, 0.f, 0.f, 0.f, 0.f, 0.f, 0.f};
#pragma unroll
  for (int j = 0; j < 12; ++j) {
    const __half2 h0 = __builtin_bit_cast(__half2, v[j].x);
    const __half2 h1 = __builtin_bit_cast(__half2, v[j].y);
    const __half2 h2 = __builtin_bit_cast(__half2, v[j].z);
    const __half2 h3 = __builtin_bit_cast(__half2, v[j].w);
    const float wj = w[j];
    acc[0] = fmaf(wj, __low2float(h0), acc[0]);
    acc[1] = fmaf(wj, __high2float(h0), acc[1]);
    acc[2] = fmaf(wj, __low2float(h1), acc[2]);
    acc[3] = fmaf(wj, __high2float(h1), acc[3]);
    acc[4] = fmaf(wj, __low2float(h2), acc[4]);
    acc[5] = fmaf(wj, __high2float(h2), acc[5]);
    acc[6] = fmaf(wj, __low2float(h3), acc[6]);
    acc[7] = fmaf(wj, __high2float(h3), acc[7]);
  }

  // phase 4: butterfly-reduce the 4 corner groups (lanes l, l+16, l+32, l+48)
#pragma unroll
  for (int c = 0; c < 8; ++c) acc[c] += __shfl_xor(acc[c], 32, 64);
#pragma unroll
  for (int c = 0; c < 8; ++c) acc[c] += __shfl_xor(acc[c], 16, 64);

  if (lane < 16) {
    float* op = out + (size_t)q * CCH + lane * 8;
    floatx4 lo4 = {acc[0], acc[1], acc[2], acc[3]};
    floatx4 hi4 = {acc[4], acc[5], acc[6], acc[7]};
    __builtin_nontemporal_store(lo4, (floatx4*)op);
    __builtin_nontemporal_store(hi4, (floatx4*)(op + 4));
  }
}

// -------- fallback: fused, direct (C,H,W) gather (used only if ws too small) --------
__global__ void fused_fallback(const float* __restrict__ query,
                               const float* __restrict__ pe,
                               const float* __restrict__ f0,
                               const float* __restrict__ f1,
                               const float* __restrict__ f2,
                               const float* __restrict__ Wa0, const float* __restrict__ ba0,
                               const float* __restrict__ Wo0, const float* __restrict__ bo0,
                               const float* __restrict__ Wa1, const float* __restrict__ ba1,
                               const float* __restrict__ Wo1, const float* __restrict__ bo1,
                               const float* __restrict__ Wa2, const float* __restrict__ ba2,
                               const float* __restrict__ Wo2, const float* __restrict__ bo2,
                               float* __restrict__ out) {
  const int lane = threadIdx.x & 63;
  const int wid = threadIdx.x >> 6;
  int q = blockIdx.x * 4 + wid;
  q = __builtin_amdgcn_readfirstlane(q);
  if (q >= NQ) return;
  const float qx = query[q * 3 + 0];
  const float qy = query[q * 3 + 1];
  const float qz = query[q * 3 + 2];
  const float* pep = pe + (size_t)q * PDIM;
  const int c0i = lane * 2, c1i = lane * 2 + 1;
  float accx = 0.0f, accy = 0.0f;
#pragma unroll
  for (int pl = 0; pl < 3; ++pl) {
    const float* Wa = (pl == 0) ? Wa0 : ((pl == 1) ? Wa1 : Wa2);
    const float* ba = (pl == 0) ? ba0 : ((pl == 1) ? ba1 : ba2);
    const float* Wo = (pl == 0) ? Wo0 : ((pl == 1) ? Wo1 : Wo2);
    const float* bo = (pl == 0) ? bo0 : ((pl == 1) ? bo1 : bo2);
    const float* f = (pl == 0) ? f0 : ((pl == 1) ? f1 : f2);
    float la[4] = {ba[0], ba[1], ba[2], ba[3]};
    float of[8];
    for (int d = 0; d < 8; ++d) of[d] = bo[d];
    for (int j = 0; j < PDIM; ++j) {
      const float pj = pep[j];
      for (int k = 0; k < 4; ++k) la[k] = fmaf(pj, Wa[j * 4 + k], la[k]);
      for (int d = 0; d < 8; ++d) of[d] = fmaf(pj, Wo[j * 8 + d], of[d]);
    }
    const float m = fmaxf(fmaxf(la[0], la[1]), fmaxf(la[2], la[3]));
    float e[4], s = 0.0f;
    for (int k = 0; k < 4; ++k) { e[k] = expf(la[k] - m); s += e[k]; }
    const float inv = 1.0f / s;
    const float ca = (pl == 2) ? qy : qx;
    const float cb = (pl == 0) ? qy : qz;
    for (int k = 0; k < 4; ++k) {
      const float gy = ca + of[k * 2 + 0];
      const float gx = cb + of[k * 2 + 1];
      float x = ((gx + 1.0f) * (float)WDIM - 1.0f) * 0.5f;
      float y = ((gy + 1.0f) * (float)HDIM - 1.0f) * 0.5f;
      x = fminf(fmaxf(x, 0.0f), (float)(WDIM - 1));
      y = fminf(fmaxf(y, 0.0f), (float)(HDIM - 1));
      const float x0f = floorf(x), y0f = floorf(y);
      const float wx = x - x0f, wy = y - y0f;
      const int xi0 = (int)x0f, yi0 = (int)y0f;
      const int xi1 = min(xi0 + 1, WDIM - 1);
      const int yi1 = min(yi0 + 1, HDIM - 1);
      const float a = e[k] * inv;
      const float w00 = a * (1.0f - wx) * (1.0f - wy);
      const float w01 = a * wx * (1.0f - wy);
      const float w10 = a * (1.0f - wx) * wy;
      const float w11 = a * wx * wy;
      const size_t p00 = (size_t)(yi0 * WDIM + xi0);
      const size_t p01 = (size_t)(yi0 * WDIM + xi1);
      const size_t p10 = (size_t)(yi1 * WDIM + xi0);
      const size_t p11 = (size_t)(yi1 * WDIM + xi1);
      const float* fa = f + (size_t)c0i * HW;
      const float* fb = f + (size_t)c1i * HW;
      accx += w00 * fa[p00] + w01 * fa[p01] + w10 * fa[p10] + w11 * fa[p11];
      accy += w00 * fb[p00] + w01 * fb[p01] + w10 * fb[p10] + w11 * fb[p11];
    }
  }
  *(float2*)(out + (size_t)q * CCH + lane * 2) = make_float2(accx, accy);
}

extern "C" void kernel_launch(void* const* d_in, const int* in_sizes, int n_in,
                              void* d_out, int out_size, void* d_ws, size_t ws_size,
                              hipStream_t stream) {
  const float* query = (const float*)d_in[0];
  const float* pe    = (const float*)d_in[1];
  const float* feat0 = (const float*)d_in[2];
  const float* Wa0   = (const float*)d_in[3];
  const float* ba0   = (const float*)d_in[4];
  const float* Wo0   = (const float*)d_in[5];
  const float* bo0   = (const float*)d_in[6];
  const float* feat1 = (const float*)d_in[7];
  const float* Wa1   = (const float*)d_in[8];
  const float* ba1   = (const float*)d_in[9];
  const float* Wo1   = (const float*)d_in[10];
  const float* bo1   = (const float*)d_in[11];
  const float* feat2 = (const float*)d_in[12];
  const float* Wa2   = (const float*)d_in[13];
  const float* ba2   = (const float*)d_in[14];
  const float* Wo2   = (const float*)d_in[15];
  const float* bo2   = (const float*)d_in[16];
  float* out = (float*)d_out;

  const size_t featT_elems = 3ull * HW * (CCH / 2);  // __half2 count
  // layout: featT (half2) | rec (NQ*RECW u32) | counts | offs
  const size_t need = featT_elems * 4 + (size_t)NQ * RECW * 4 + (size_t)NBIN * 8;

  if (ws_size >= need) {
    __half2* featT = (__half2*)d_ws;
    unsigned int* rec = (unsigned int*)(d_ws) + featT_elems;  // featT is 4B elems
    unsigned int* counts = rec + (size_t)NQ * RECW;
    unsigned int* offs = counts + NBIN;

    (void)hipMemsetAsync(counts, 0, NBIN * sizeof(unsigned int), stream);
    hist_kernel<<<dim3(WBLK), dim3(256), 0, stream>>>(query, counts);
    scan_kernel<<<dim3(1), dim3(1024), 0, stream>>>(counts, offs);
    fused_prep_kernel<<<dim3(WBLK + TBLK), dim3(256), 0, stream>>>(
        feat0, feat1, feat2, featT, query, pe, offs,
        Wa0, ba0, Wo0, bo0, Wa1, ba1, Wo1, bo1, Wa2, ba2, Wo2, bo2, rec);
    sample_kernel<<<dim3(NQ / 4), dim3(256), 0, stream>>>(rec, featT, out);
  } else {
    fused_fallback<<<dim3((NQ + 3) / 4), dim3(256), 0, stream>>>(
        query, pe, feat0, feat1, feat2,
        Wa0, ba0, Wo0, bo0, Wa1, ba1, Wo1, bo1, Wa2, ba2, Wo2, bo2, out);
  }
}